// Round 17
// baseline (142.785 us; speedup 1.0000x reference)
//
#include <hip/hip_runtime.h>
#include <hip/hip_bf16.h>

#define N_ROWS 8192
#define DIM 256
#define TEMP_INV 20.0f
// logit2 = cos * 20*log2(e); with int8 quantized (x127) operands the exact
// i32 dot is converted via C2F = 20*log2(e)/127^2, then exp2.
#define C2F 1.7889516e-3f

typedef __attribute__((ext_vector_type(4))) int i32x4;

// ---------------------------------------------------------------------------
// 1) Merged prep (int8 quantization) -- R13-proven; adds done[] zeroing.
// ---------------------------------------------------------------------------
__global__ void __launch_bounds__(256) prep_kernel(
    const float* __restrict__ anc, const float* __restrict__ pos,
    const float* __restrict__ neg, char* __restrict__ a8,
    char* __restrict__ p8, char* __restrict__ n8,
    float* __restrict__ diag, float* __restrict__ rowsum,
    float* __restrict__ out, int* __restrict__ done) {
  __shared__ __align__(16) char t8[8192];   // one k-major i8 panel
  const int lane = threadIdx.x & 63;
  const int w = threadIdx.x >> 6;

  if (blockIdx.x < 2048) {                   // ---- anchor rows ----
    if (blockIdx.x < 32 && threadIdx.x == 0) done[blockIdx.x] = 0;
    int wid = blockIdx.x * 4 + w;            // row 0..8191
    float4 a = reinterpret_cast<const float4*>(anc + (size_t)wid * DIM)[lane];
    float4 p = reinterpret_cast<const float4*>(pos + (size_t)wid * DIM)[lane];
    float d  = a.x * p.x + a.y * p.y + a.z * p.z + a.w * p.w;
    float na = a.x * a.x + a.y * a.y + a.z * a.z + a.w * a.w;
    float np = p.x * p.x + p.y * p.y + p.z * p.z + p.w * p.w;
#pragma unroll
    for (int m = 32; m; m >>= 1) {
      d  += __shfl_xor(d, m);
      na += __shfl_xor(na, m);
      np += __shfl_xor(np, m);
    }
    float rna = fmaxf(sqrtf(na), 1e-8f);
    float s = 127.0f / rna;
    int q0 = (int)rintf(a.x * s), q1 = (int)rintf(a.y * s);
    int q2 = (int)rintf(a.z * s), q3 = (int)rintf(a.w * s);
    unsigned pk = (q0 & 0xFF) | ((q1 & 0xFF) << 8) |
                  ((q2 & 0xFF) << 16) | ((q3 & 0xFF) << 24);
    *reinterpret_cast<unsigned*>(a8 + (size_t)wid * DIM + (lane << 2)) = pk;
    if (lane == 0) {
      diag[wid] = TEMP_INV * d / (rna * fmaxf(sqrtf(np), 1e-8f));
      rowsum[wid] = 0.f;
    }
    return;
  }
  // ---- P/N k-major i8 panels ----
  const int b = blockIdx.x - 2048;           // 0..511
  if (b == 511 && threadIdx.x == 0) out[0] = 0.f;
  const float* src = (b < 256) ? pos : neg;
  char* dst = (b < 256) ? p8 : n8;
  const int pb = b & 255;
#pragma unroll
  for (int i = 0; i < 8; ++i) {
    int r = i * 4 + w;                       // row (col of B) within panel
    float4 v = reinterpret_cast<const float4*>(src + (size_t)(pb * 32 + r) * DIM)[lane];
    float ss = v.x * v.x + v.y * v.y + v.z * v.z + v.w * v.w;
#pragma unroll
    for (int m = 32; m; m >>= 1) ss += __shfl_xor(ss, m);
    float s = 127.0f / fmaxf(sqrtf(ss), 1e-8f);
    int q0 = (int)rintf(v.x * s), q1 = (int)rintf(v.y * s);
    int q2 = (int)rintf(v.z * s), q3 = (int)rintf(v.w * s);
    unsigned pk = (q0 & 0xFF) | ((q1 & 0xFF) << 8) |
                  ((q2 & 0xFF) << 16) | ((q3 & 0xFF) << 24);
    // lane holds k = 4*lane..4*lane+3 -> k0 = lane>>2, off = 4*(lane&3)
    *reinterpret_cast<unsigned*>(t8 + ((lane >> 2) << 9) + (r << 4) +
                                 ((lane & 3) << 2)) = pk;
  }
  __syncthreads();
  const uint4* ts = reinterpret_cast<const uint4*>(t8);
  uint4* outp = reinterpret_cast<uint4*>(dst + (size_t)pb * 8192);
  outp[threadIdx.x]       = ts[threadIdx.x];
  outp[threadIdx.x + 256] = ts[threadIdx.x + 256];
}

// ---------------------------------------------------------------------------
// 2) Fused GEMM + row-sum(exp2) + loss tail -- i8 MFMA, 64-row waves.
//    R16 analysis: at 32-row waves the LDS-read demand is 4MB/CU (~20-24us
//    of LDS-port time, >50% of kernel). LDS traffic scales as 1/rows-per-
//    wave -> revert to R13's 64-row cluster (2MB/CU) and keep R16's
//    residency gains: ring-3 24KB + __launch_bounds__(256,4). R13 compiled
//    to exactly 64 VGPR + 64 AGPR = 128 regs = the (256,4) budget -> 4
//    waves/SIMD, 4 blocks/CU; grid 32x32=1024 = fully resident, no tail.
//    Ring-3 discipline (R16-proven): prologue STAGE(0,1); per iter wait
//    vmcnt(2) (tail 0) -> own panel-`it` loads done, panel it+1 in flight;
//    barrier; STAGE(it+2) into panel it-1's slot (readers passed barrier).
//    Loss tail (saves the 3rd launch): after this block's rowsum atomics,
//    threadfence + per-rb ticket; the 32nd cc-block re-reads its 256 rows
//    coherently (atomicAdd(p,0.f)), computes log(v)-diag, atomicAdds out.
//    k-major panels -> ds_reads linear-in-lane, 0 conflicts (R4-R16).
//    MFMA C layout (shape-determined, verified): col=lane&15, row=(lane>>4)*4+q.
// ---------------------------------------------------------------------------
__global__ void __launch_bounds__(256, 4) fused_kernel(
    const char* __restrict__ a8, const char* __restrict__ p8,
    const char* __restrict__ n8, float* __restrict__ rowsum,
    const float* __restrict__ diag, float* __restrict__ out,
    int* __restrict__ done) {
  __shared__ __align__(16) char smem[3 * 8192];   // ring of 3 x 8KB panels
  __shared__ int ticket;
  const int tid  = threadIdx.x;
  const int lane = tid & 63;
  const int w    = tid >> 6;          // 0..3
  const int rb   = blockIdx.x >> 5;   // 0..31 (256 rows each)
  const int cc   = blockIdx.x & 31;   // 0..31 (512 cols = 16 panels each)
  const char* B = (cc < 16) ? (p8 + (size_t)cc * 16 * 8192)
                            : (n8 + (size_t)(cc - 16) * 16 * 8192);
  const int row0 = rb * 256 + w * 64;
  const int ar = lane & 15;           // fragment row/col index
  const int g  = lane >> 4;           // k-group within fragment
  const int vbase = (g << 9) + (ar << 4);  // lane byte-offset within a panel

  // A fragments: 64 rows x K=256 i8 = 4rf x 4km x i32x4 (64 regs, pinned).
  i32x4 af[4][4];
#pragma unroll
  for (int rf = 0; rf < 4; ++rf)
#pragma unroll
    for (int km = 0; km < 4; ++km) {
      af[rf][km] = *reinterpret_cast<const i32x4*>(
          a8 + (size_t)(row0 + rf * 16 + ar) * DIM + km * 64 + g * 16);
      asm volatile("" : "+v"(af[rf][km]));   // non-remat def: stays resident
    }

  // Stage panel `p` (8KB contiguous) into ring slot `slot`: 2 loads/wave.
#define STAGE(slot, p)                                                         \
  {                                                                            \
    _Pragma("unroll")                                                          \
    for (int j = 0; j < 2; ++j) {                                              \
      const int L = (w << 1) | j;                                              \
      const char* src = B + ((size_t)(p) << 13) + (L << 10) + (lane << 4);     \
      char* dst = (char*)smem + ((slot) << 13) + (L << 10);                    \
      __builtin_amdgcn_global_load_lds(                                        \
          (const __attribute__((address_space(1))) void*)src,                  \
          (__attribute__((address_space(3))) void*)dst, 16, 0, 0);             \
    }                                                                          \
  }

#define MMI(A, Bf, C) __builtin_amdgcn_mfma_i32_16x16x64_i8((A), (Bf), (C), 0, 0, 0)

  // One cf-cluster: 4 ds_read_b128 + 16 MFMA + 16-elem exp2 epilogue.
#define CLUSTER(CFOFF)                                                         \
  {                                                                            \
    i32x4 bf[4];                                                               \
    _Pragma("unroll")                                                          \
    for (int km = 0; km < 4; ++km)                                             \
      bf[km] = *reinterpret_cast<const i32x4*>(pbase + (km << 11) + (CFOFF));  \
    i32x4 acc[4];                                                              \
    _Pragma("unroll")                                                          \
    for (int rf = 0; rf < 4; ++rf) acc[rf] = MMI(af[rf][0], bf[0], zeroi);     \
    _Pragma("unroll")                                                          \
    for (int km = 1; km < 4; ++km)                                             \
      _Pragma("unroll")                                                        \
      for (int rf = 0; rf < 4; ++rf)                                           \
        acc[rf] = MMI(af[rf][km], bf[km], acc[rf]);                            \
    _Pragma("unroll")                                                          \
    for (int rf = 0; rf < 4; ++rf)                                             \
      _Pragma("unroll")                                                        \
      for (int q = 0; q < 4; ++q)                                              \
        psum[rf][q] += __builtin_amdgcn_exp2f((float)acc[rf][q] * C2F);        \
  }

  float psum[4][4];
#pragma unroll
  for (int rf = 0; rf < 4; ++rf)
#pragma unroll
    for (int q = 0; q < 4; ++q) psum[rf][q] = 0.f;
  const i32x4 zeroi = {0, 0, 0, 0};

  STAGE(0, 0);
  STAGE(1, 1);          // 4 loads/wave outstanding
  int rd = 0;           // slot of panel `it` (= it % 3)
  for (int it = 0; it < 16; ++it) {
    // Own panel-`it` loads done; panel it+1 stays in flight (counted).
    if (it <= 14) asm volatile("s_waitcnt vmcnt(2)" ::: "memory");
    else          asm volatile("s_waitcnt vmcnt(0)" ::: "memory");
    __builtin_amdgcn_s_barrier();
    const char* pbase = smem + (rd << 13) + vbase;
    const int st = (rd == 0) ? 2 : rd - 1;   // (it+2)%3 == (it-1)%3
    CLUSTER(0);                        // cf0 (cols ar)
    if (it <= 13) STAGE(st, it + 2);   // slot of panel it-1: readers retired
    CLUSTER(256);                      // cf1 (cols 16+ar)
    rd = (rd == 2) ? 0 : rd + 1;
  }

  // Reduce over the 16 column-lanes (vary ar, keep g); accumulate per row.
#pragma unroll
  for (int rf = 0; rf < 4; ++rf)
#pragma unroll
    for (int q = 0; q < 4; ++q) {
      float s = psum[rf][q];
      s += __shfl_xor(s, 1);
      s += __shfl_xor(s, 2);
      s += __shfl_xor(s, 4);
      s += __shfl_xor(s, 8);
      if (ar == 0)
        atomicAdd(rowsum + row0 + rf * 16 + g * 4 + q, s);
    }

  // ---- fused loss tail: the 32nd cc-block for this rb computes the loss ----
  __threadfence();            // order our atomics before the ticket
  __syncthreads();
  if (tid == 0) ticket = atomicAdd(&done[rb], 1);
  __syncthreads();
  if (ticket == 31) {
    int r = rb * 256 + tid;   // 256 rows, 256 threads
    float v = atomicAdd(&rowsum[r], 0.0f);   // coherent read (device scope)
    float l = logf(v) - diag[r];
#pragma unroll
    for (int m = 32; m; m >>= 1) l += __shfl_xor(l, m);
    if ((tid & 63) == 0) atomicAdd(out, l * (1.0f / (float)N_ROWS));
  }
#undef STAGE
#undef CLUSTER
#undef MMI
}

// ---------------------------------------------------------------------------
extern "C" void kernel_launch(void* const* d_in, const int* in_sizes, int n_in,
                              void* d_out, int out_size, void* d_ws, size_t ws_size,
                              hipStream_t stream) {
  const float* anc = (const float*)d_in[0];
  const float* pos = (const float*)d_in[1];
  const float* neg = (const float*)d_in[2];
  char* ws = (char*)d_ws;
  char* a8 = ws;                                  // [8192][256] i8 row-major
  char* p8 = ws + (size_t)N_ROWS * DIM;           // k-major i8 panels (2MB)
  char* n8 = p8 + (size_t)N_ROWS * DIM;
  float* diag = (float*)(ws + (size_t)3 * N_ROWS * DIM);  // 8192 f32
  float* rowsum = diag + N_ROWS;                          // 8192 f32
  int* done = (int*)(rowsum + N_ROWS);                    // 32 i32
  float* out = (float*)d_out;

  prep_kernel<<<2048 + 512, 256, 0, stream>>>(anc, pos, neg, a8, p8, n8, diag, rowsum, out, done);
  fused_kernel<<<32 * 32, 256, 0, stream>>>(a8, p8, n8, rowsum, diag, out, done);
}

// Round 18
// 62.551 us; speedup vs baseline: 2.2827x; 2.2827x over previous
//
#include <hip/hip_runtime.h>
#include <hip/hip_bf16.h>

#define N_ROWS 8192
#define DIM 256
#define TEMP_INV 20.0f
// logit2 = cos * 20*log2(e); with int8 quantized (x127) operands the exact
// i32 dot is converted via C2F = 20*log2(e)/127^2, then exp2.
#define C2F 1.7889516e-3f

typedef __attribute__((ext_vector_type(4))) int i32x4;

// ---------------------------------------------------------------------------
// 1) Merged prep (int8 quantization) -- unchanged from R13/R16 (proven).
// ---------------------------------------------------------------------------
__global__ void __launch_bounds__(256) prep_kernel(
    const float* __restrict__ anc, const float* __restrict__ pos,
    const float* __restrict__ neg, char* __restrict__ a8,
    char* __restrict__ p8, char* __restrict__ n8,
    float* __restrict__ diag, float* __restrict__ rowsum,
    float* __restrict__ out) {
  __shared__ __align__(16) char t8[8192];   // one k-major i8 panel
  const int lane = threadIdx.x & 63;
  const int w = threadIdx.x >> 6;

  if (blockIdx.x < 2048) {                   // ---- anchor rows ----
    int wid = blockIdx.x * 4 + w;            // row 0..8191
    float4 a = reinterpret_cast<const float4*>(anc + (size_t)wid * DIM)[lane];
    float4 p = reinterpret_cast<const float4*>(pos + (size_t)wid * DIM)[lane];
    float d  = a.x * p.x + a.y * p.y + a.z * p.z + a.w * p.w;
    float na = a.x * a.x + a.y * a.y + a.z * a.z + a.w * a.w;
    float np = p.x * p.x + p.y * p.y + p.z * p.z + p.w * p.w;
#pragma unroll
    for (int m = 32; m; m >>= 1) {
      d  += __shfl_xor(d, m);
      na += __shfl_xor(na, m);
      np += __shfl_xor(np, m);
    }
    float rna = fmaxf(sqrtf(na), 1e-8f);
    float s = 127.0f / rna;
    int q0 = (int)rintf(a.x * s), q1 = (int)rintf(a.y * s);
    int q2 = (int)rintf(a.z * s), q3 = (int)rintf(a.w * s);
    unsigned pk = (q0 & 0xFF) | ((q1 & 0xFF) << 8) |
                  ((q2 & 0xFF) << 16) | ((q3 & 0xFF) << 24);
    *reinterpret_cast<unsigned*>(a8 + (size_t)wid * DIM + (lane << 2)) = pk;
    if (lane == 0) {
      diag[wid] = TEMP_INV * d / (rna * fmaxf(sqrtf(np), 1e-8f));
      rowsum[wid] = 0.f;
    }
    return;
  }
  // ---- P/N k-major i8 panels ----
  const int b = blockIdx.x - 2048;           // 0..511
  if (b == 511 && threadIdx.x == 0) out[0] = 0.f;
  const float* src = (b < 256) ? pos : neg;
  char* dst = (b < 256) ? p8 : n8;
  const int pb = b & 255;
#pragma unroll
  for (int i = 0; i < 8; ++i) {
    int r = i * 4 + w;                       // row (col of B) within panel
    float4 v = reinterpret_cast<const float4*>(src + (size_t)(pb * 32 + r) * DIM)[lane];
    float ss = v.x * v.x + v.y * v.y + v.z * v.z + v.w * v.w;
#pragma unroll
    for (int m = 32; m; m >>= 1) ss += __shfl_xor(ss, m);
    float s = 127.0f / fmaxf(sqrtf(ss), 1e-8f);
    int q0 = (int)rintf(v.x * s), q1 = (int)rintf(v.y * s);
    int q2 = (int)rintf(v.z * s), q3 = (int)rintf(v.w * s);
    unsigned pk = (q0 & 0xFF) | ((q1 & 0xFF) << 8) |
                  ((q2 & 0xFF) << 16) | ((q3 & 0xFF) << 24);
    // lane holds k = 4*lane..4*lane+3 -> k0 = lane>>2, off = 4*(lane&3)
    *reinterpret_cast<unsigned*>(t8 + ((lane >> 2) << 9) + (r << 4) +
                                 ((lane & 3) << 2)) = pk;
  }
  __syncthreads();
  const uint4* ts = reinterpret_cast<const uint4*>(t8);
  uint4* outp = reinterpret_cast<uint4*>(dst + (size_t)pb * 8192);
  outp[threadIdx.x]       = ts[threadIdx.x];
  outp[threadIdx.x + 256] = ts[threadIdx.x + 256];
}

// ---------------------------------------------------------------------------
// 2) Fused GEMM + row-sum(exp2) -- i8 MFMA, 64-row waves, ring-3, (256,4).
//    R17 post-mortem: the loss-tail's extra live state pushed the 64-row
//    loop past the exact 128-reg (256,4) cap -> scratch spill (WRITE 4->26MB)
//    + per-block threadfence L2 writebacks. Both reverted; separate loss
//    kernel restored.
//    This round = R13's exact main loop (64-row waves: LDS-read 2MB/CU ~10us
//    < 17.4us i8 MFMA floor, so MFMA-dominant) + R16's proven ring-3 24KB
//    (residency) + (256,4). R13 compiled to 64 VGPR + 64 AGPR = 128 = the
//    (256,4) budget with NOTHING else live -> should fit spill-free.
//    Grid 32 rb x 32 cc = 1024 = 4 blocks/CU fully resident, zero tail.
//    Ring-3 discipline (R16-proven): prologue STAGE(0,1); per iter wait
//    vmcnt(2) (tail 0); barrier; STAGE(it+2) into panel it-1's slot.
//    k-major panels -> ds_reads linear-in-lane, 0 conflicts (R4-R17).
//    MFMA C layout (shape-determined, verified): col=lane&15, row=(lane>>4)*4+q.
// ---------------------------------------------------------------------------
__global__ void __launch_bounds__(256, 4) fused_kernel(
    const char* __restrict__ a8, const char* __restrict__ p8,
    const char* __restrict__ n8, float* __restrict__ rowsum) {
  __shared__ __align__(16) char smem[3 * 8192];   // ring of 3 x 8KB panels
  const int tid  = threadIdx.x;
  const int lane = tid & 63;
  const int w    = tid >> 6;          // 0..3
  const int rb   = blockIdx.x >> 5;   // 0..31 (256 rows each)
  const int cc   = blockIdx.x & 31;   // 0..31 (512 cols = 16 panels each)
  const char* B = (cc < 16) ? (p8 + (size_t)cc * 16 * 8192)
                            : (n8 + (size_t)(cc - 16) * 16 * 8192);
  const int row0 = rb * 256 + w * 64;
  const int ar = lane & 15;           // fragment row/col index
  const int g  = lane >> 4;           // k-group within fragment
  const int vbase = (g << 9) + (ar << 4);  // lane byte-offset within a panel

  // A fragments: 64 rows x K=256 i8 = 4rf x 4km x i32x4 (64 regs, pinned).
  i32x4 af[4][4];
#pragma unroll
  for (int rf = 0; rf < 4; ++rf)
#pragma unroll
    for (int km = 0; km < 4; ++km) {
      af[rf][km] = *reinterpret_cast<const i32x4*>(
          a8 + (size_t)(row0 + rf * 16 + ar) * DIM + km * 64 + g * 16);
      asm volatile("" : "+v"(af[rf][km]));   // non-remat def: stays resident
    }

  // Stage panel `p` (8KB contiguous) into ring slot `slot`: 2 loads/wave.
#define STAGE(slot, p)                                                         \
  {                                                                            \
    _Pragma("unroll")                                                          \
    for (int j = 0; j < 2; ++j) {                                              \
      const int L = (w << 1) | j;                                              \
      const char* src = B + ((size_t)(p) << 13) + (L << 10) + (lane << 4);     \
      char* dst = (char*)smem + ((slot) << 13) + (L << 10);                    \
      __builtin_amdgcn_global_load_lds(                                        \
          (const __attribute__((address_space(1))) void*)src,                  \
          (__attribute__((address_space(3))) void*)dst, 16, 0, 0);             \
    }                                                                          \
  }

#define MMI(A, Bf, C) __builtin_amdgcn_mfma_i32_16x16x64_i8((A), (Bf), (C), 0, 0, 0)

  // One cf-cluster: 4 ds_read_b128 + 16 MFMA + 16-elem exp2 epilogue.
#define CLUSTER(CFOFF)                                                         \
  {                                                                            \
    i32x4 bf[4];                                                               \
    _Pragma("unroll")                                                          \
    for (int km = 0; km < 4; ++km)                                             \
      bf[km] = *reinterpret_cast<const i32x4*>(pbase + (km << 11) + (CFOFF));  \
    i32x4 acc[4];                                                              \
    _Pragma("unroll")                                                          \
    for (int rf = 0; rf < 4; ++rf) acc[rf] = MMI(af[rf][0], bf[0], zeroi);     \
    _Pragma("unroll")                                                          \
    for (int km = 1; km < 4; ++km)                                             \
      _Pragma("unroll")                                                        \
      for (int rf = 0; rf < 4; ++rf)                                           \
        acc[rf] = MMI(af[rf][km], bf[km], acc[rf]);                            \
    _Pragma("unroll")                                                          \
    for (int rf = 0; rf < 4; ++rf)                                             \
      _Pragma("unroll")                                                        \
      for (int q = 0; q < 4; ++q)                                              \
        psum[rf][q] += __builtin_amdgcn_exp2f((float)acc[rf][q] * C2F);        \
  }

  float psum[4][4];
#pragma unroll
  for (int rf = 0; rf < 4; ++rf)
#pragma unroll
    for (int q = 0; q < 4; ++q) psum[rf][q] = 0.f;
  const i32x4 zeroi = {0, 0, 0, 0};

  STAGE(0, 0);
  STAGE(1, 1);          // 4 loads/wave outstanding
  int rd = 0;           // slot of panel `it` (= it % 3)
  for (int it = 0; it < 16; ++it) {
    // Own panel-`it` loads done; panel it+1 stays in flight (counted).
    if (it <= 14) asm volatile("s_waitcnt vmcnt(2)" ::: "memory");
    else          asm volatile("s_waitcnt vmcnt(0)" ::: "memory");
    __builtin_amdgcn_s_barrier();
    const char* pbase = smem + (rd << 13) + vbase;
    const int st = (rd == 0) ? 2 : rd - 1;   // (it+2)%3 == (it-1)%3
    CLUSTER(0);                        // cf0 (cols ar)
    if (it <= 13) STAGE(st, it + 2);   // slot of panel it-1: readers retired
    CLUSTER(256);                      // cf1 (cols 16+ar)
    rd = (rd == 2) ? 0 : rd + 1;
  }

  // Reduce over the 16 column-lanes (vary ar, keep g); accumulate per row.
#pragma unroll
  for (int rf = 0; rf < 4; ++rf)
#pragma unroll
    for (int q = 0; q < 4; ++q) {
      float s = psum[rf][q];
      s += __shfl_xor(s, 1);
      s += __shfl_xor(s, 2);
      s += __shfl_xor(s, 4);
      s += __shfl_xor(s, 8);
      if (ar == 0)
        atomicAdd(rowsum + row0 + rf * 16 + g * 4 + q, s);
    }
#undef STAGE
#undef CLUSTER
#undef MMI
}

// ---------------------------------------------------------------------------
// 3) loss: grid 16 x 512 thr, one row per thread;
//    out[0] (+)= block-partials / N   (out zero-initialized in prep).
// ---------------------------------------------------------------------------
__global__ void __launch_bounds__(512) loss_kernel(
    const float* __restrict__ rowsum, const float* __restrict__ diag,
    float* __restrict__ out) {
  __shared__ float sh[8];
  int i = blockIdx.x * 512 + threadIdx.x;    // exactly covers 8192 rows
  float acc = logf(rowsum[i]) - diag[i];
#pragma unroll
  for (int m = 32; m; m >>= 1) acc += __shfl_xor(acc, m);
  if ((threadIdx.x & 63) == 0) sh[threadIdx.x >> 6] = acc;
  __syncthreads();
  if (threadIdx.x == 0) {
    float t = 0.f;
#pragma unroll
    for (int j = 0; j < 8; ++j) t += sh[j];
    atomicAdd(out, t / (float)N_ROWS);
  }
}

// ---------------------------------------------------------------------------
extern "C" void kernel_launch(void* const* d_in, const int* in_sizes, int n_in,
                              void* d_out, int out_size, void* d_ws, size_t ws_size,
                              hipStream_t stream) {
  const float* anc = (const float*)d_in[0];
  const float* pos = (const float*)d_in[1];
  const float* neg = (const float*)d_in[2];
  char* ws = (char*)d_ws;
  char* a8 = ws;                                  // [8192][256] i8 row-major
  char* p8 = ws + (size_t)N_ROWS * DIM;           // k-major i8 panels (2MB)
  char* n8 = p8 + (size_t)N_ROWS * DIM;
  float* diag = (float*)(ws + (size_t)3 * N_ROWS * DIM);  // 8192 f32
  float* rowsum = diag + N_ROWS;                          // 8192 f32
  float* out = (float*)d_out;

  prep_kernel<<<2048 + 512, 256, 0, stream>>>(anc, pos, neg, a8, p8, n8, diag, rowsum, out);
  fused_kernel<<<32 * 32, 256, 0, stream>>>(a8, p8, n8, rowsum);
  loss_kernel<<<16, 512, 0, stream>>>(rowsum, diag, out);
}

// Round 19
// 57.187 us; speedup vs baseline: 2.4968x; 1.0938x over previous
//
#include <hip/hip_runtime.h>
#include <hip/hip_bf16.h>

#define N_ROWS 8192
#define DIM 256
#define TEMP_INV 20.0f
// logit2 = cos * 20*log2(e); with int8 quantized (x127) operands the exact
// i32 dot is converted via C2F = 20*log2(e)/127^2, then exp2.
#define C2F 1.7889516e-3f

typedef __attribute__((ext_vector_type(4))) int i32x4;

// ---------------------------------------------------------------------------
// 1) Merged prep (int8 quantization) -- unchanged from R13/R16 (proven).
// ---------------------------------------------------------------------------
__global__ void __launch_bounds__(256) prep_kernel(
    const float* __restrict__ anc, const float* __restrict__ pos,
    const float* __restrict__ neg, char* __restrict__ a8,
    char* __restrict__ p8, char* __restrict__ n8,
    float* __restrict__ diag, float* __restrict__ rowsum,
    float* __restrict__ out) {
  __shared__ __align__(16) char t8[8192];   // one k-major i8 panel
  const int lane = threadIdx.x & 63;
  const int w = threadIdx.x >> 6;

  if (blockIdx.x < 2048) {                   // ---- anchor rows ----
    int wid = blockIdx.x * 4 + w;            // row 0..8191
    float4 a = reinterpret_cast<const float4*>(anc + (size_t)wid * DIM)[lane];
    float4 p = reinterpret_cast<const float4*>(pos + (size_t)wid * DIM)[lane];
    float d  = a.x * p.x + a.y * p.y + a.z * p.z + a.w * p.w;
    float na = a.x * a.x + a.y * a.y + a.z * a.z + a.w * a.w;
    float np = p.x * p.x + p.y * p.y + p.z * p.z + p.w * p.w;
#pragma unroll
    for (int m = 32; m; m >>= 1) {
      d  += __shfl_xor(d, m);
      na += __shfl_xor(na, m);
      np += __shfl_xor(np, m);
    }
    float rna = fmaxf(sqrtf(na), 1e-8f);
    float s = 127.0f / rna;
    int q0 = (int)rintf(a.x * s), q1 = (int)rintf(a.y * s);
    int q2 = (int)rintf(a.z * s), q3 = (int)rintf(a.w * s);
    unsigned pk = (q0 & 0xFF) | ((q1 & 0xFF) << 8) |
                  ((q2 & 0xFF) << 16) | ((q3 & 0xFF) << 24);
    *reinterpret_cast<unsigned*>(a8 + (size_t)wid * DIM + (lane << 2)) = pk;
    if (lane == 0) {
      diag[wid] = TEMP_INV * d / (rna * fmaxf(sqrtf(np), 1e-8f));
      rowsum[wid] = 0.f;
    }
    return;
  }
  // ---- P/N k-major i8 panels ----
  const int b = blockIdx.x - 2048;           // 0..511
  if (b == 511 && threadIdx.x == 0) out[0] = 0.f;
  const float* src = (b < 256) ? pos : neg;
  char* dst = (b < 256) ? p8 : n8;
  const int pb = b & 255;
#pragma unroll
  for (int i = 0; i < 8; ++i) {
    int r = i * 4 + w;                       // row (col of B) within panel
    float4 v = reinterpret_cast<const float4*>(src + (size_t)(pb * 32 + r) * DIM)[lane];
    float ss = v.x * v.x + v.y * v.y + v.z * v.z + v.w * v.w;
#pragma unroll
    for (int m = 32; m; m >>= 1) ss += __shfl_xor(ss, m);
    float s = 127.0f / fmaxf(sqrtf(ss), 1e-8f);
    int q0 = (int)rintf(v.x * s), q1 = (int)rintf(v.y * s);
    int q2 = (int)rintf(v.z * s), q3 = (int)rintf(v.w * s);
    unsigned pk = (q0 & 0xFF) | ((q1 & 0xFF) << 8) |
                  ((q2 & 0xFF) << 16) | ((q3 & 0xFF) << 24);
    // lane holds k = 4*lane..4*lane+3 -> k0 = lane>>2, off = 4*(lane&3)
    *reinterpret_cast<unsigned*>(t8 + ((lane >> 2) << 9) + (r << 4) +
                                 ((lane & 3) << 2)) = pk;
  }
  __syncthreads();
  const uint4* ts = reinterpret_cast<const uint4*>(t8);
  uint4* outp = reinterpret_cast<uint4*>(dst + (size_t)pb * 8192);
  outp[threadIdx.x]       = ts[threadIdx.x];
  outp[threadIdx.x + 256] = ts[threadIdx.x + 256];
}

// ---------------------------------------------------------------------------
// 2) Fused GEMM + row-sum(exp2) -- R16's exact kernel, (256,6).
//    R18 post-mortem: 64-row waves spill at the 128-reg (256,4) cap (WRITE
//    4->23.5MB) -- 64-row and high-residency are mutually exclusive. R16
//    (32-row, ring-3, 45.4us clean) is the best config; its compiled size is
//    44 VGPR + 32 AGPR = 76 regs, far under the (256,4) cap of 128 -- the
//    residency binder was the REQUESTED wave budget. (256,6): cap 85 >= 76
//    (no spill), LDS 6 x 24KB = 144 <= 160KB -> up to 6 blocks/CU = 24
//    waves/CU. The one robust cross-round correlation (combined pipe util
//    tracks waves/SIMD: 2w->61%, 2.6w->68%, 3.2w->75%) predicts ~90%.
//    Everything else byte-identical to R16: BM=128 (32 rows/wave, af =
//    2rf x 4km = 32 regs pinned), ring-3 8KB k-major panels, counted
//    vmcnt(2)/0, ONE barrier/panel, ds_reads linear-in-lane (0 conflicts
//    R4-R18), exact i32 dot, epilogue exp2f(acc * C2F).
//    MFMA C layout (shape-determined, verified): col=lane&15, row=(lane>>4)*4+q.
// ---------------------------------------------------------------------------
__global__ void __launch_bounds__(256, 6) fused_kernel(
    const char* __restrict__ a8, const char* __restrict__ p8,
    const char* __restrict__ n8, float* __restrict__ rowsum) {
  __shared__ __align__(16) char smem[3 * 8192];   // ring of 3 x 8KB panels
  const int tid  = threadIdx.x;
  const int lane = tid & 63;
  const int w    = tid >> 6;          // 0..3
  const int rb   = blockIdx.x >> 5;   // 0..63 (128 rows each)
  const int cc   = blockIdx.x & 31;   // 0..31 (512 cols = 16 panels each)
  const char* B = (cc < 16) ? (p8 + (size_t)cc * 16 * 8192)
                            : (n8 + (size_t)(cc - 16) * 16 * 8192);
  const int row0 = rb * 128 + w * 32;
  const int ar = lane & 15;           // fragment row/col index
  const int g  = lane >> 4;           // k-group within fragment
  const int vbase = (g << 9) + (ar << 4);  // lane byte-offset within a panel

  // A fragments: 32 rows x K=256 i8 = 2rf x 4km x i32x4 (32 regs, pinned).
  i32x4 af[2][4];
#pragma unroll
  for (int rf = 0; rf < 2; ++rf)
#pragma unroll
    for (int km = 0; km < 4; ++km) {
      af[rf][km] = *reinterpret_cast<const i32x4*>(
          a8 + (size_t)(row0 + rf * 16 + ar) * DIM + km * 64 + g * 16);
      asm volatile("" : "+v"(af[rf][km]));   // non-remat def: stays resident
    }

  // Stage panel `p` (8KB contiguous) into ring slot `slot`: 2 loads/wave.
#define STAGE(slot, p)                                                         \
  {                                                                            \
    _Pragma("unroll")                                                          \
    for (int j = 0; j < 2; ++j) {                                              \
      const int L = (w << 1) | j;                                              \
      const char* src = B + ((size_t)(p) << 13) + (L << 10) + (lane << 4);     \
      char* dst = (char*)smem + ((slot) << 13) + (L << 10);                    \
      __builtin_amdgcn_global_load_lds(                                        \
          (const __attribute__((address_space(1))) void*)src,                  \
          (__attribute__((address_space(3))) void*)dst, 16, 0, 0);             \
    }                                                                          \
  }

#define MMI(A, Bf, C) __builtin_amdgcn_mfma_i32_16x16x64_i8((A), (Bf), (C), 0, 0, 0)

  // One cf-cluster: 4 ds_read_b128 + 8 MFMA + 8-elem exp2 epilogue.
#define CLUSTER(CFOFF)                                                         \
  {                                                                            \
    i32x4 bf[4];                                                               \
    _Pragma("unroll")                                                          \
    for (int km = 0; km < 4; ++km)                                             \
      bf[km] = *reinterpret_cast<const i32x4*>(pbase + (km << 11) + (CFOFF));  \
    i32x4 acc[2];                                                              \
    _Pragma("unroll")                                                          \
    for (int rf = 0; rf < 2; ++rf) acc[rf] = MMI(af[rf][0], bf[0], zeroi);     \
    _Pragma("unroll")                                                          \
    for (int km = 1; km < 4; ++km)                                             \
      _Pragma("unroll")                                                        \
      for (int rf = 0; rf < 2; ++rf)                                           \
        acc[rf] = MMI(af[rf][km], bf[km], acc[rf]);                            \
    _Pragma("unroll")                                                          \
    for (int rf = 0; rf < 2; ++rf)                                             \
      _Pragma("unroll")                                                        \
      for (int q = 0; q < 4; ++q)                                              \
        psum[rf][q] += __builtin_amdgcn_exp2f((float)acc[rf][q] * C2F);        \
  }

  float psum[2][4];
#pragma unroll
  for (int rf = 0; rf < 2; ++rf)
#pragma unroll
    for (int q = 0; q < 4; ++q) psum[rf][q] = 0.f;
  const i32x4 zeroi = {0, 0, 0, 0};

  STAGE(0, 0);
  STAGE(1, 1);          // 4 loads/wave outstanding
  int rd = 0;           // slot of panel `it` (= it % 3)
  for (int it = 0; it < 16; ++it) {
    // Own panel-`it` loads done; panel it+1 stays in flight (counted).
    if (it <= 14) asm volatile("s_waitcnt vmcnt(2)" ::: "memory");
    else          asm volatile("s_waitcnt vmcnt(0)" ::: "memory");
    __builtin_amdgcn_s_barrier();
    const char* pbase = smem + (rd << 13) + vbase;
    const int st = (rd == 0) ? 2 : rd - 1;   // (it+2)%3 == (it-1)%3
    CLUSTER(0);                        // cf0 (cols ar)
    if (it <= 13) STAGE(st, it + 2);   // slot of panel it-1: readers retired
    CLUSTER(256);                      // cf1 (cols 16+ar)
    rd = (rd == 2) ? 0 : rd + 1;
  }

  // Reduce over the 16 column-lanes (vary ar, keep g); accumulate per row.
#pragma unroll
  for (int rf = 0; rf < 2; ++rf)
#pragma unroll
    for (int q = 0; q < 4; ++q) {
      float s = psum[rf][q];
      s += __shfl_xor(s, 1);
      s += __shfl_xor(s, 2);
      s += __shfl_xor(s, 4);
      s += __shfl_xor(s, 8);
      if (ar == 0)
        atomicAdd(rowsum + row0 + rf * 16 + g * 4 + q, s);
    }
#undef STAGE
#undef CLUSTER
#undef MMI
}

// ---------------------------------------------------------------------------
// 3) loss: grid 16 x 512 thr, one row per thread;
//    out[0] (+)= block-partials / N   (out zero-initialized in prep).
// ---------------------------------------------------------------------------
__global__ void __launch_bounds__(512) loss_kernel(
    const float* __restrict__ rowsum, const float* __restrict__ diag,
    float* __restrict__ out) {
  __shared__ float sh[8];
  int i = blockIdx.x * 512 + threadIdx.x;    // exactly covers 8192 rows
  float acc = logf(rowsum[i]) - diag[i];
#pragma unroll
  for (int m = 32; m; m >>= 1) acc += __shfl_xor(acc, m);
  if ((threadIdx.x & 63) == 0) sh[threadIdx.x >> 6] = acc;
  __syncthreads();
  if (threadIdx.x == 0) {
    float t = 0.f;
#pragma unroll
    for (int j = 0; j < 8; ++j) t += sh[j];
    atomicAdd(out, t / (float)N_ROWS);
  }
}

// ---------------------------------------------------------------------------
extern "C" void kernel_launch(void* const* d_in, const int* in_sizes, int n_in,
                              void* d_out, int out_size, void* d_ws, size_t ws_size,
                              hipStream_t stream) {
  const float* anc = (const float*)d_in[0];
  const float* pos = (const float*)d_in[1];
  const float* neg = (const float*)d_in[2];
  char* ws = (char*)d_ws;
  char* a8 = ws;                                  // [8192][256] i8 row-major
  char* p8 = ws + (size_t)N_ROWS * DIM;           // k-major i8 panels (2MB)
  char* n8 = p8 + (size_t)N_ROWS * DIM;
  float* diag = (float*)(ws + (size_t)3 * N_ROWS * DIM);  // 8192 f32
  float* rowsum = diag + N_ROWS;                          // 8192 f32
  float* out = (float*)d_out;

  prep_kernel<<<2048 + 512, 256, 0, stream>>>(anc, pos, neg, a8, p8, n8, diag, rowsum, out);
  fused_kernel<<<64 * 32, 256, 0, stream>>>(a8, p8, n8, rowsum);
  loss_kernel<<<16, 512, 0, stream>>>(rowsum, diag, out);
}